// Round 2
// baseline (125.290 us; speedup 1.0000x reference)
//
#include <hip/hip_runtime.h>

// BPNet fused forward: E=16384, ORDER=3, D=13, RANK=128, NUM_PARAMS=4.
// One wave per edge. Stage 1: lane owns rank channels {lane, lane+64}.
// Stage 2: facts staged in LDS (padded, conflict-free); lane (g,d)=(lane>>4,
// lane&15) accumulates over 32 ranks, then 2-shuffle partial reduce.
// NUM_ITERS loop in reference is idempotent -> compute one iteration.

#define DD 13
#define RK 128
#define OD 3
#define NP 4
#define FSTR 36              // padded per-group stride (dwords); 36*4B=144B, 16B-aligned
#define FSLOT (4 * FSTR)     // 144 dwords per slot

__global__ __launch_bounds__(256) void bpnet_fused(
    const float* __restrict__ nodes,      // [N, 13]
    const float* __restrict__ bp_params,  // [4, 13, 128]
    const float* __restrict__ bp_bias,    // [4, 1, 128]
    const float* __restrict__ ho_params,  // [3, 4, 128, 13]
    const float* __restrict__ ho_bias,    // [3, 4, 1, 13]
    const int*   __restrict__ edges,      // [E, 3]
    const int*   __restrict__ edge_types, // [E, 3]
    float*       __restrict__ out,        // [N, 13] (pre-zeroed)
    int E)
{
    const int lane = threadIdx.x & 63;
    const int wv   = threadIdx.x >> 6;
    const int e    = blockIdx.x * 4 + wv;

    __shared__ float fact_lds[4][OD * FSLOT];  // 4 waves * 432 dwords = 6912 B

    if (e >= E) return;

    // Wave-uniform indices -> SGPRs (scalar loads downstream).
    int et[OD], tg[OD];
#pragma unroll
    for (int o = 0; o < OD; ++o) {
        et[o] = __builtin_amdgcn_readfirstlane(edge_types[e * OD + o]);
        tg[o] = __builtin_amdgcn_readfirstlane(edges[e * OD + o]);
    }

    // Stage 1: t[o][r] = relu(nodes[tg[o],:] @ bp_params[et[o],:,:] + bias)
    float t0[OD], t1[OD];
#pragma unroll
    for (int o = 0; o < OD; ++o) {
        const float* W  = bp_params + et[o] * DD * RK;
        const float* nr = nodes + (size_t)tg[o] * DD;   // scalar base
        float nv[DD];
#pragma unroll
        for (int d = 0; d < DD; ++d) nv[d] = nr[d];     // uniform -> s_load
        float s0 = bp_bias[et[o] * RK + lane];
        float s1 = bp_bias[et[o] * RK + 64 + lane];
#pragma unroll
        for (int d = 0; d < DD; ++d) {
            s0 = fmaf(nv[d], W[d * RK + lane], s0);
            s1 = fmaf(nv[d], W[d * RK + 64 + lane], s1);
        }
        t0[o] = fmaxf(s0, 0.f);
        t1[o] = fmaxf(s1, 0.f);
    }

    // Facts -> LDS. r=lane at [g=lane>>5][rr=lane&31]; r=lane+64 at [g+2][rr].
    float* myf = fact_lds[wv];
    const int wg = lane >> 5, wr = lane & 31;
#pragma unroll
    for (int i = 0; i < OD; ++i) {
        const int j = (i + 1) % OD, k = (i + 2) % OD;
        myf[i * FSLOT + wg * FSTR + wr]       = t0[j] * t0[k];
        myf[i * FSLOT + (wg + 2) * FSTR + wr] = t1[j] * t1[k];
    }
    // Same-wave LDS ops execute in order; no barrier needed (per-wave slice).

    // Stage 2: lane (g,d); sum over r in [g*32,(g+1)*32) of fact[r]*W[r][d].
    const int g = lane >> 4;
    const int d = lane & 15;
    const int dd = (d < DD) ? d : 0;   // keep inactive lanes in-bounds
#pragma unroll
    for (int i = 0; i < OD; ++i) {
        const float* W  = ho_params + (size_t)(i * NP + et[i]) * RK * DD;
        const float* fp = myf + i * FSLOT + g * FSTR;
        float a0 = 0.f, a1 = 0.f, a2 = 0.f, a3 = 0.f;
#pragma unroll
        for (int rr = 0; rr < 32; rr += 4) {
            const float4 fv = *(const float4*)(fp + rr);      // ds_read_b128, bcast
            const float* wb = W + (g * 32 + rr) * DD + dd;    // L1-hot
            a0 = fmaf(fv.x, wb[0],      a0);
            a1 = fmaf(fv.y, wb[DD],     a1);
            a2 = fmaf(fv.z, wb[2 * DD], a2);
            a3 = fmaf(fv.w, wb[3 * DD], a3);
        }
        float v = (a0 + a1) + (a2 + a3);
        v += __shfl_xor(v, 16, 64);   // combine g pairs
        v += __shfl_xor(v, 32, 64);   // combine halves
        if (lane < DD) {
            v += ho_bias[(i * NP + et[i]) * DD + lane];
            atomicAdd(out + (size_t)tg[i] * DD + lane, v);
        }
    }
}

extern "C" void kernel_launch(void* const* d_in, const int* in_sizes, int n_in,
                              void* d_out, int out_size, void* d_ws, size_t ws_size,
                              hipStream_t stream) {
    const float* nodes      = (const float*)d_in[0];
    const float* bp_params  = (const float*)d_in[1];
    const float* bp_bias    = (const float*)d_in[2];
    const float* ho_params  = (const float*)d_in[3];
    const float* ho_bias    = (const float*)d_in[4];
    const int*   edges      = (const int*)d_in[5];
    const int*   edge_types = (const int*)d_in[6];
    float* out = (float*)d_out;

    const int E = in_sizes[5] / OD;

    // out is poisoned 0xAA before every timed call — zero it for the atomics.
    hipMemsetAsync(out, 0, (size_t)out_size * sizeof(float), stream);

    const int blocks = (E + 3) / 4;  // 4 waves (edges) per 256-thread block
    bpnet_fused<<<blocks, 256, 0, stream>>>(
        nodes, bp_params, bp_bias, ho_params, ho_bias, edges, edge_types, out, E);
}

// Round 3
// 104.984 us; speedup vs baseline: 1.1934x; 1.1934x over previous
//
#include <hip/hip_runtime.h>

// BPNet fused forward: E=16384, ORDER=3, D=13, RANK=128, NUM_PARAMS=4.
// One wave per 4 edges. Stage-1 weights (all 4 types, 26.6 KB) live in
// VGPRs distributed by rank (lane owns r=lane and r=lane+64). Stage-2 W
// rows streamed from L1/L2 as wide loads. Cross-lane reduction: 4 DPP
// stages (row-sum-of-16, pure VALU) + cndmask select + 2 shfl_xor.
// NUM_ITERS loop in reference is idempotent -> one iteration.

#define DD 13
#define RK 128
#define OD 3
#define NP 4
#define EPW 4  // edges per wave

typedef float f4 __attribute__((ext_vector_type(4)));

__device__ __forceinline__ f4 ldg4(const float* p) {  // 4B-aligned 16B load
    f4 r;
    __builtin_memcpy(&r, p, 16);
    return r;
}

template <int CTRL>
__device__ __forceinline__ float dpp_add(float x) {
    int p = __builtin_amdgcn_update_dpp(0, __float_as_int(x), CTRL, 0xF, 0xF, false);
    return x + __int_as_float(p);
}

__device__ __forceinline__ float row_sum16(float x) {
    x = dpp_add<0xB1>(x);   // quad_perm [1,0,3,2]  : xor 1
    x = dpp_add<0x4E>(x);   // quad_perm [2,3,0,1]  : xor 2
    x = dpp_add<0x141>(x);  // row_half_mirror      : xor 7 (pairs quads)
    x = dpp_add<0x140>(x);  // row_mirror           : xor 15 (pairs 8-groups)
    return x;               // every lane holds the sum over its row of 16
}

__global__ __launch_bounds__(256) void bpnet_fused(
    const float* __restrict__ nodes,      // [N, 13]
    const float* __restrict__ bp_params,  // [4, 13, 128]
    const float* __restrict__ bp_bias,    // [4, 1, 128]
    const float* __restrict__ ho_params,  // [3, 4, 128, 13]
    const float* __restrict__ ho_bias,    // [3, 4, 1, 13]
    const int*   __restrict__ edges,      // [E, 3]
    const int*   __restrict__ edge_types, // [E, 3]
    float*       __restrict__ out,        // [N, 13] (pre-zeroed)
    int E)
{
    const int lane = threadIdx.x & 63;
    const int wv   = threadIdx.x >> 6;
    const int e0   = (blockIdx.x * 4 + wv) * EPW;

    // ---- resident tables in VGPRs (loaded once, amortized over EPW edges) --
    float w1a[NP][DD], w1b[NP][DD], b1a[NP], b1b[NP];
#pragma unroll
    for (int ty = 0; ty < NP; ++ty) {
#pragma unroll
        for (int d = 0; d < DD; ++d) {
            w1a[ty][d] = bp_params[(ty * DD + d) * RK + lane];
            w1b[ty][d] = bp_params[(ty * DD + d) * RK + 64 + lane];
        }
        b1a[ty] = bp_bias[ty * RK + lane];
        b1b[ty] = bp_bias[ty * RK + 64 + lane];
    }
    const int dsel = lane & 15;

#pragma unroll 1
    for (int ke = 0; ke < EPW; ++ke) {
        const int e = e0 + ke;
        int et[OD], tg[OD];
#pragma unroll
        for (int o = 0; o < OD; ++o) {  // uniform addresses -> s_load
            et[o] = edge_types[e * OD + o];
            tg[o] = edges[e * OD + o];
        }

        // ---- stage 1: t[o][r] = relu(n . W1[ty][:,r] + b1[ty][r]) ----
        float t0[OD], t1[OD];
#pragma unroll
        for (int o = 0; o < OD; ++o) {
            const float* nr = nodes + (size_t)tg[o] * DD;  // uniform -> s_load
            float nv[DD];
#pragma unroll
            for (int d = 0; d < DD; ++d) nv[d] = nr[d];
            float s0 = 0.f, s1 = 0.f;
            switch (et[o]) {
#define S1CASE(T)                                              \
            case T:                                            \
                s0 = b1a[T]; s1 = b1b[T];                      \
                _Pragma("unroll")                              \
                for (int d = 0; d < DD; ++d) {                 \
                    s0 = fmaf(nv[d], w1a[T][d], s0);           \
                    s1 = fmaf(nv[d], w1b[T][d], s1);           \
                }                                              \
                break;
            S1CASE(0) S1CASE(1) S1CASE(2) S1CASE(3)
#undef S1CASE
            default: break;
            }
            t0[o] = fmaxf(s0, 0.f);
            t1[o] = fmaxf(s1, 0.f);
        }

        // ---- stage 2, slot-sequential ----
#pragma unroll
        for (int i = 0; i < OD; ++i) {
            const int j = (i + 1) % OD, k2 = (i + 2) % OD;
            const float f0 = t0[j] * t0[k2];
            const float f1 = t1[j] * t1[k2];
            const float* rbase = ho_params + (size_t)(i * NP + et[i]) * RK * DD;
            const float* r0 = rbase + lane * DD;          // row r = lane
            const float* r1 = rbase + (lane + 64) * DD;   // row r = lane+64
            f4 a0 = ldg4(r0), a1 = ldg4(r0 + 4), a2 = ldg4(r0 + 8);
            float a3 = r0[12];
            f4 g0 = ldg4(r1), g1 = ldg4(r1 + 4), g2 = ldg4(r1 + 8);
            float g3 = r1[12];

            float c[DD];
            c[0]  = fmaf(f1, g0.x, f0 * a0.x);
            c[1]  = fmaf(f1, g0.y, f0 * a0.y);
            c[2]  = fmaf(f1, g0.z, f0 * a0.z);
            c[3]  = fmaf(f1, g0.w, f0 * a0.w);
            c[4]  = fmaf(f1, g1.x, f0 * a1.x);
            c[5]  = fmaf(f1, g1.y, f0 * a1.y);
            c[6]  = fmaf(f1, g1.z, f0 * a1.z);
            c[7]  = fmaf(f1, g1.w, f0 * a1.w);
            c[8]  = fmaf(f1, g2.x, f0 * a2.x);
            c[9]  = fmaf(f1, g2.y, f0 * a2.y);
            c[10] = fmaf(f1, g2.z, f0 * a2.z);
            c[11] = fmaf(f1, g2.w, f0 * a2.w);
            c[12] = fmaf(f1, g3,   f0 * a3);

            // per-chain row sums (13 independent DPP chains, pure VALU)
#pragma unroll
            for (int d = 0; d < DD; ++d) c[d] = row_sum16(c[d]);

            // lane (row, dsel) picks chain dsel (v_cmp hoisted out of loop)
            float q = c[0];
#pragma unroll
            for (int d = 1; d < DD; ++d) q = (dsel == d) ? c[d] : q;
            // combine the 4 rows
            q += __shfl_xor(q, 16, 64);
            q += __shfl_xor(q, 32, 64);

            if (lane < DD) {
                const float* bb = ho_bias + (i * NP + et[i]) * DD;  // uniform
                q += bb[lane];
                atomicAdd(out + (size_t)tg[i] * DD + lane, q);
            }
        }
    }
}

extern "C" void kernel_launch(void* const* d_in, const int* in_sizes, int n_in,
                              void* d_out, int out_size, void* d_ws, size_t ws_size,
                              hipStream_t stream) {
    const float* nodes      = (const float*)d_in[0];
    const float* bp_params  = (const float*)d_in[1];
    const float* bp_bias    = (const float*)d_in[2];
    const float* ho_params  = (const float*)d_in[3];
    const float* ho_bias    = (const float*)d_in[4];
    const int*   edges      = (const int*)d_in[5];
    const int*   edge_types = (const int*)d_in[6];
    float* out = (float*)d_out;

    const int E = in_sizes[5] / OD;

    // out is poisoned 0xAA before every timed call — zero it for the atomics.
    hipMemsetAsync(out, 0, (size_t)out_size * sizeof(float), stream);

    const int blocks = E / (4 * EPW);  // 4 waves/block, EPW edges/wave
    bpnet_fused<<<blocks, 256, 0, stream>>>(
        nodes, bp_params, bp_bias, ho_params, ho_bias, edges, edge_types, out, E);
}